// Round 4
// baseline (484.559 us; speedup 1.0000x reference)
//
#include <hip/hip_runtime.h>
#include <hip/hip_bf16.h>

// Problem constants
#define NNODES 100000
#define NEDGES 300000
#define FIN 128
#define HDIM 256
#define NLAYERS 3
#define MPAD 100096  // 782 * 128 — all GEMMs compute exactly MPAD rows, no predicates

typedef float f32x4 __attribute__((ext_vector_type(4)));
typedef short bf16x8 __attribute__((ext_vector_type(8)));

__device__ inline float bf2f(unsigned short u) {
    union { unsigned int i; float f; } v;
    v.i = ((unsigned int)u) << 16;
    return v.f;
}
__device__ inline unsigned short f2bf(float f) {  // RNE
    union { float f; unsigned int i; } v;
    v.f = f;
    return (unsigned short)((v.i + 0x7fffu + ((v.i >> 16) & 1u)) >> 16);
}

// 16-byte async global->LDS (dest = wave-uniform base + lane*16)
__device__ __forceinline__ void gll16(const unsigned short* g, unsigned short* l) {
    __builtin_amdgcn_global_load_lds(
        (const __attribute__((address_space(1))) unsigned int*)g,
        (__attribute__((address_space(3))) unsigned int*)l, 16, 0, 0);
}

// ---------------------------------------------------------------------------
// Counted-vmcnt pipelined MFMA GEMM, 128x256 tile, 8 waves (512 threads).
// Wave (wr=wid>>2, wc=wid&3) owns a 64x64 sub-tile via 4x4 of 16x16x32 MFMA.
// BK=32, TRIPLE-buffered LDS (72 KiB): A tile 128xBK (8KB) + B tile 256xBK
// (16KB) per buffer. Per wave per K-step: 3 gll16 (1 A + 2 B); two stages in
// flight -> s_waitcnt vmcnt(3) before each stage's compute (vmcnt(0) last).
// Race audit: reads at iter t hit buf[t%3]; stage(t+2) issued AFTER
// barrier(t), whose buffer's readers (iter t-1) all retired pre-barrier.
// SWAPPED OPERANDS: acc[i][j] = mfma(b[j], a[i], acc) computes the same C
// but with D layout lane&15 = C-row, kq*4+reg = 4 CONSECUTIVE C-cols ->
// epilogue packs ushort4 and does 16x 8B stores/thread (vs 64x 2B).
// Staging: global_load_lds w=16, LINEAR LDS dest; ds_read_b128 conflicts
// avoided by pre-swizzled global SOURCE + same XOR on read (slot ^= (row>>1)&3).
// A: bf16 [.][K] row-major.  Bt: bf16 [256][K] (pre-transposed).  C: bf16.
// M multiple of 128 (grid.y = M/128); grid.x = 1.
// ---------------------------------------------------------------------------
template <int K, bool BIAS, bool RELU>
__global__ __launch_bounds__(512, 4) void gemm_lds_k(
    const unsigned short* __restrict__ A, const unsigned short* __restrict__ Bt,
    const float* __restrict__ bias, unsigned short* __restrict__ C) {
    constexpr int BK = 32;        // 64 B per LDS row
    constexpr int NT = K / BK;    // 4 (K=128) or 8 (K=256)
    __shared__ unsigned short sA[3][128 * BK];
    __shared__ unsigned short sB[3][256 * BK];

    const int tid  = threadIdx.x;
    const int lane = tid & 63;
    const int wid  = tid >> 6;         // 0..7
    const int r15  = lane & 15;
    const int kq   = lane >> 4;        // 0..3
    const int wr   = wid >> 2;         // wave row-tile (0/1)
    const int wc   = wid & 3;          // wave col-tile (0..3)
    const int rowblk = blockIdx.y * 128;

    // Staging geometry: lane L writes LDS row (base + L>>2), phys slot (L&3).
    // Phys slot p at row r holds logical k-slot p ^ ((r>>1)&3)  (involution).
    // A: wave w covers rows w*16..+15 (1 gll16). B: rows w*32+q*16..+15, q=0,1.
    int rA = wid * 16 + (lane >> 2);
    int sltA = (lane & 3) ^ ((rA >> 1) & 3);
    const unsigned short* gA = A + (size_t)(rowblk + rA) * K + sltA * 8;
    const int ldsA = wid * 16 * BK;    // wave-uniform

    const unsigned short* gB[2];
    int ldsB[2];
#pragma unroll
    for (int q = 0; q < 2; ++q) {
        int rB = wid * 32 + q * 16 + (lane >> 2);
        int sltB = (lane & 3) ^ ((rB >> 1) & 3);
        gB[q] = Bt + (size_t)rB * K + sltB * 8;
        ldsB[q] = (wid * 32 + q * 16) * BK;   // wave-uniform
    }

    // Read-side swizzled fragment offsets (elements)
    const int sread = ((kq ^ ((r15 >> 1) & 3)) * 8);
    int aoff[4], boff[4];
#pragma unroll
    for (int i = 0; i < 4; ++i) {
        aoff[i] = (wr * 64 + i * 16 + r15) * BK + sread;
        boff[i] = (wc * 64 + i * 16 + r15) * BK + sread;
    }

    f32x4 acc[4][4] = {};

    // prologue: stage K-tiles 0 and 1 into bufs 0 and 1 (6 loads in flight/wave)
#pragma unroll
    for (int s = 0; s < 2; ++s) {
        gll16(gA + s * BK, &sA[s][ldsA]);
        gll16(gB[0] + s * BK, &sB[s][ldsB[0]]);
        gll16(gB[1] + s * BK, &sB[s][ldsB[1]]);
    }

#pragma unroll
    for (int t = 0; t < NT; ++t) {
        // counted drain: stage(t) landed; stage(t+1)'s 3 loads stay in flight
        if (t + 1 < NT) {
            asm volatile("s_waitcnt vmcnt(3)" ::: "memory");
        } else {
            asm volatile("s_waitcnt vmcnt(0)" ::: "memory");
        }
        __builtin_amdgcn_s_barrier();
        // issue stage(t+2) AFTER the barrier (its buffer's readers were iter
        // t-1, all retired before any wave passed this barrier)
        if (t + 2 < NT) {
            gll16(gA + (t + 2) * BK, &sA[(t + 2) % 3][ldsA]);
            gll16(gB[0] + (t + 2) * BK, &sB[(t + 2) % 3][ldsB[0]]);
            gll16(gB[1] + (t + 2) * BK, &sB[(t + 2) % 3][ldsB[1]]);
        }
        bf16x8 a[4], b[4];
#pragma unroll
        for (int i = 0; i < 4; ++i) a[i] = *(const bf16x8*)&sA[t % 3][aoff[i]];
#pragma unroll
        for (int j = 0; j < 4; ++j) b[j] = *(const bf16x8*)&sB[t % 3][boff[j]];
        // swapped operands: D[m'=C-col][n'=C-row]; lane&15 = C-row,
        // kq*4+reg = C-col (4 consecutive cols per lane)
#pragma unroll
        for (int i = 0; i < 4; ++i)
#pragma unroll
            for (int j = 0; j < 4; ++j)
                acc[i][j] = __builtin_amdgcn_mfma_f32_16x16x32_bf16(b[j], a[i], acc[i][j], 0, 0, 0);
    }

    // Epilogue: lane holds C[row][colb..colb+3] per frag — one 8B store each
#pragma unroll
    for (int i = 0; i < 4; ++i) {
        int row = rowblk + wr * 64 + i * 16 + r15;
#pragma unroll
        for (int j = 0; j < 4; ++j) {
            int colb = wc * 64 + j * 16 + kq * 4;
            float v0 = acc[i][j][0], v1 = acc[i][j][1], v2 = acc[i][j][2], v3 = acc[i][j][3];
            if (BIAS) {
                float4 bb = ((const float4*)bias)[colb >> 2];
                v0 += bb.x; v1 += bb.y; v2 += bb.z; v3 += bb.w;
            }
            if (RELU) {
                v0 = fmaxf(v0, 0.0f); v1 = fmaxf(v1, 0.0f);
                v2 = fmaxf(v2, 0.0f); v3 = fmaxf(v3, 0.0f);
            }
            ushort4 o;
            o.x = f2bf(v0); o.y = f2bf(v1); o.z = f2bf(v2); o.w = f2bf(v3);
            *(ushort4*)&C[(size_t)row * HDIM + colb] = o;
        }
    }
}

// ---------------------------------------------------------------------------
// Weight prep: W[nm][K][256] fp32 -> Wt[nm][256][K] bf16 (transpose+convert)
// ---------------------------------------------------------------------------
__global__ void wprep_k(const float* __restrict__ W, unsigned short* __restrict__ Wt,
                        int K, int total) {
    int i = blockIdx.x * blockDim.x + threadIdx.x;
    if (i >= total) return;
    int mat = i / (K * 256);
    int r = i - mat * (K * 256);
    int k = r >> 8, p = r & 255;
    Wt[(size_t)mat * K * 256 + (size_t)p * K + k] = f2bf(W[i]);
}

// Straight fp32 -> bf16 convert (no transpose), vectorized x4
__global__ void conv_k(const float* __restrict__ W, unsigned short* __restrict__ o, int n4) {
    int i = blockIdx.x * blockDim.x + threadIdx.x;
    if (i >= n4) return;
    float4 v = ((const float4*)W)[i];
    ushort4 u;
    u.x = f2bf(v.x); u.y = f2bf(v.y); u.z = f2bf(v.z); u.w = f2bf(v.w);
    ((ushort4*)o)[i] = u;
}

// foldb[c] = sum_j b2[j] * G0[j][c]   (G0 = gcn_w layer 0, row-major fp32)
__global__ void foldbias_k(const float* __restrict__ b2, const float* __restrict__ g0,
                           float* __restrict__ fb) {
    int c = threadIdx.x;  // one block of 256
    float s = 0.0f;
#pragma unroll 8
    for (int j = 0; j < HDIM; ++j) s += b2[j] * g0[(size_t)j * HDIM + c];
    fb[c] = s;
}

// ---------------------------------------------------------------------------
// CSR build utilities
// ---------------------------------------------------------------------------
__global__ void zero_k(unsigned* __restrict__ p, int n) {
    int i = blockIdx.x * blockDim.x + threadIdx.x;
    if (i < n) p[i] = 0u;
}

__global__ void count_k(const int* __restrict__ dst, unsigned* __restrict__ cnt, int E) {
    int e = blockIdx.x * blockDim.x + threadIdx.x;
    if (e < E) atomicAdd(&cnt[dst[e]], 1u);
}

// scan1 also computes dinv and zeroes cnt (cursor reuse) — saves 2 launches
__global__ __launch_bounds__(256) void scan1_k(unsigned* __restrict__ cnt,
                                               int* __restrict__ rs,
                                               unsigned* __restrict__ blocksum,
                                               float* __restrict__ dinv, int N) {
    __shared__ unsigned tmp[256];
    int tid = threadIdx.x;
    int gid = blockIdx.x * 256 + tid;
    unsigned v = (gid < N) ? cnt[gid] : 0u;
    if (gid < N) {
        dinv[gid] = 1.0f / sqrtf((float)(v + 1u));  // +1 = self loop
        cnt[gid] = 0u;                               // reset for cursor use
    }
    tmp[tid] = v;
    __syncthreads();
#pragma unroll
    for (int off = 1; off < 256; off <<= 1) {
        unsigned t = (tid >= off) ? tmp[tid - off] : 0u;
        __syncthreads();
        tmp[tid] += t;
        __syncthreads();
    }
    if (gid < N) rs[gid] = (int)(tmp[tid] - v);
    if (tid == 255) blocksum[blockIdx.x] = tmp[tid];
}

__global__ __launch_bounds__(512) void scan2_k(unsigned* __restrict__ blocksum, int nb) {
    __shared__ unsigned tmp[512];
    int tid = threadIdx.x;
    unsigned v = (tid < nb) ? blocksum[tid] : 0u;
    tmp[tid] = v;
    __syncthreads();
#pragma unroll
    for (int off = 1; off < 512; off <<= 1) {
        unsigned t = (tid >= off) ? tmp[tid - off] : 0u;
        __syncthreads();
        tmp[tid] += t;
        __syncthreads();
    }
    if (tid < nb) blocksum[tid] = tmp[tid] - v;
}

__global__ void scan3_k(int* __restrict__ rs, const unsigned* __restrict__ blocksum, int N, int E) {
    int gid = blockIdx.x * blockDim.x + threadIdx.x;
    if (gid < N) rs[gid] += (int)blocksum[gid >> 8];
    if (gid == 0) rs[N] = E;
}

// fill_k packs (src, weight) into one int2 per edge — single 8B load in gather
__global__ void fill_k(const int* __restrict__ src, const int* __restrict__ dst,
                       const int* __restrict__ rs, unsigned* __restrict__ cursor,
                       const float* __restrict__ dinv,
                       int2* __restrict__ edata, int E) {
    int e = blockIdx.x * blockDim.x + threadIdx.x;
    if (e >= E) return;
    int s = src[e], d = dst[e];
    int pos = rs[d] + (int)atomicAdd(&cursor[d], 1u);
    float w = dinv[s] * dinv[d];
    edata[pos] = make_int2(s, __float_as_int(w));
}

// ---------------------------------------------------------------------------
// CSR gather-aggregate (bf16 m), fused self-loop + bias + ReLU.
// One wave per node; ushort4 (4 cols) per lane.
// Cooperative edge-metadata load + register shuffle broadcast + 4-wide
// unrolled independent row gathers. Masked slots carry (s=0, w=0.0).
// ---------------------------------------------------------------------------
template <bool OUTF32>
__global__ __launch_bounds__(256) void gather_k(const int* __restrict__ rs,
                                                const int2* __restrict__ edata,
                                                const float* __restrict__ dinv,
                                                const unsigned short* __restrict__ m,
                                                const float* __restrict__ bias,
                                                void* __restrict__ out, int N) {
    int node = blockIdx.x * 4 + (threadIdx.x >> 6);
    int lane = threadIdx.x & 63;
    if (node >= N) return;
    int beg = rs[node], end = rs[node + 1];
    float d = dinv[node];
    float w0 = d * d;
    ushort4 u = ((const ushort4*)(m + (size_t)node * HDIM))[lane];
    float ax = bf2f(u.x) * w0, ay = bf2f(u.y) * w0, az = bf2f(u.z) * w0, aw = bf2f(u.w) * w0;

    for (int base = beg; base < end; base += 64) {
        int2 ed = (base + lane < end) ? edata[base + lane] : make_int2(0, 0);
        int take = end - base;
        if (take > 64) take = 64;
        for (int e = 0; e < take; e += 4) {
            int s0 = __shfl(ed.x, e + 0);
            int s1 = __shfl(ed.x, e + 1);
            int s2 = __shfl(ed.x, e + 2);
            int s3 = __shfl(ed.x, e + 3);
            float wq0 = __int_as_float(__shfl(ed.y, e + 0));
            float wq1 = __int_as_float(__shfl(ed.y, e + 1));
            float wq2 = __int_as_float(__shfl(ed.y, e + 2));
            float wq3 = __int_as_float(__shfl(ed.y, e + 3));
            ushort4 v0 = ((const ushort4*)(m + (size_t)s0 * HDIM))[lane];
            ushort4 v1 = ((const ushort4*)(m + (size_t)s1 * HDIM))[lane];
            ushort4 v2 = ((const ushort4*)(m + (size_t)s2 * HDIM))[lane];
            ushort4 v3 = ((const ushort4*)(m + (size_t)s3 * HDIM))[lane];
            ax += bf2f(v0.x) * wq0; ay += bf2f(v0.y) * wq0;
            az += bf2f(v0.z) * wq0; aw += bf2f(v0.w) * wq0;
            ax += bf2f(v1.x) * wq1; ay += bf2f(v1.y) * wq1;
            az += bf2f(v1.z) * wq1; aw += bf2f(v1.w) * wq1;
            ax += bf2f(v2.x) * wq2; ay += bf2f(v2.y) * wq2;
            az += bf2f(v2.z) * wq2; aw += bf2f(v2.w) * wq2;
            ax += bf2f(v3.x) * wq3; ay += bf2f(v3.y) * wq3;
            az += bf2f(v3.z) * wq3; aw += bf2f(v3.w) * wq3;
        }
    }

    float4 b = ((const float4*)bias)[lane];
    ax = fmaxf(ax + b.x, 0.0f);
    ay = fmaxf(ay + b.y, 0.0f);
    az = fmaxf(az + b.z, 0.0f);
    aw = fmaxf(aw + b.w, 0.0f);
    if (OUTF32) {
        float4 o = {ax, ay, az, aw};
        ((float4*)out)[(size_t)node * 64 + lane] = o;
    } else {
        ushort4 o;
        o.x = f2bf(ax); o.y = f2bf(ay); o.z = f2bf(az); o.w = f2bf(aw);
        ((ushort4*)out)[(size_t)node * 64 + lane] = o;
    }
}

extern "C" void kernel_launch(void* const* d_in, const int* in_sizes, int n_in,
                              void* d_out, int out_size, void* d_ws, size_t ws_size,
                              hipStream_t stream) {
    const float* x  = (const float*)d_in[0];
    const int* ei   = (const int*)d_in[1];
    const float* w1 = (const float*)d_in[2];
    const float* b1 = (const float*)d_in[3];
    const float* w2 = (const float*)d_in[4];
    const float* b2 = (const float*)d_in[5];
    const float* gw = (const float*)d_in[6];
    const float* gb = (const float*)d_in[7];

    const int N = NNODES, E = NEDGES;
    const int* src = ei;
    const int* dst = ei + E;

    // Workspace layout (~158 MB)
    char* p = (char*)d_ws;
    unsigned short* h1   = (unsigned short*)p; p += (size_t)MPAD * HDIM * 2;  // 51.2 MB
    unsigned short* h    = (unsigned short*)p; p += (size_t)MPAD * HDIM * 2;
    unsigned short* m    = (unsigned short*)p; p += (size_t)MPAD * HDIM * 2;
    unsigned short* w1t  = (unsigned short*)p; p += (size_t)FIN * HDIM * 2;
    unsigned short* gwt  = (unsigned short*)p; p += (size_t)NLAYERS * HDIM * HDIM * 2;
    unsigned short* w2c  = (unsigned short*)p; p += (size_t)HDIM * HDIM * 2;   // w2 bf16 row-major
    unsigned short* fBt  = (unsigned short*)p; p += (size_t)HDIM * HDIM * 2;   // folded W2*G0, Bt layout
    float* foldb = (float*)p;          p += (size_t)HDIM * 4;                  // folded bias b2*G0
    unsigned* cnt = (unsigned*)p;      p += (size_t)N * 4;
    float* dinv = (float*)p;           p += (size_t)N * 4;
    int* rs = (int*)p;                 p += (size_t)(N + 1) * 4 + 12;
    unsigned* blocksum = (unsigned*)p; p += 512 * 4;
    int2* edata = (int2*)p;            p += (size_t)E * 8;   // packed (src, weight)

    // xb: x converted to bf16 [MPAD][FIN] — reuses the idle m buffer (25.6 MB < 51.2 MB)
    unsigned short* xb = m;

    const int nb = (N + 255) / 256;             // 391
    const dim3 ggrid(1, MPAD / 128);            // 782 blocks, 128x256 tiles

    // ---- Weight conversion + x -> bf16 ----
    wprep_k<<<(FIN * 256 + 255) / 256, 256, 0, stream>>>(w1, w1t, FIN, FIN * 256);
    wprep_k<<<(NLAYERS * HDIM * 256 + 255) / 256, 256, 0, stream>>>(gw, gwt, HDIM, NLAYERS * HDIM * 256);
    conv_k<<<(HDIM * HDIM / 4 + 255) / 256, 256, 0, stream>>>(w2, w2c, HDIM * HDIM / 4);
    conv_k<<<(N * FIN / 4 + 255) / 256, 256, 0, stream>>>(x, xb, N * FIN / 4);

    // ---- Fold: fBt[c][k'] = sum_j G0[j][c]*W2[k'][j];  foldb[c] = sum_j b2[j]*G0[j][c]
    foldbias_k<<<1, 256, 0, stream>>>(b2, gw, foldb);
    gemm_lds_k<HDIM, false, false><<<dim3(1, 2), 512, 0, stream>>>(gwt, w2c, nullptr, fBt);

    // ---- CSR build (6 launches) ----
    zero_k<<<nb, 256, 0, stream>>>(cnt, N);
    count_k<<<(E + 255) / 256, 256, 0, stream>>>(dst, cnt, E);
    scan1_k<<<nb, 256, 0, stream>>>(cnt, rs, blocksum, dinv, N);
    scan2_k<<<1, 512, 0, stream>>>(blocksum, nb);
    scan3_k<<<nb + 1, 256, 0, stream>>>(rs, blocksum, N, E);
    fill_k<<<(E + 255) / 256, 256, 0, stream>>>(src, dst, rs, cnt, dinv, edata, E);

    // ---- Encoder GEMM1: h1 = relu(xb @ W1 + b1) ----
    gemm_lds_k<FIN, true, true><<<ggrid, 512, 0, stream>>>(xb, w1t, b1, h1);

    // ---- Layer 0 (folded): m = h1 @ (W2*G0) + b2*G0  (overwrites xb — already consumed)
    gemm_lds_k<HDIM, true, false><<<ggrid, 512, 0, stream>>>(h1, fBt, foldb, m);
    gather_k<false><<<(N + 3) / 4, 256, 0, stream>>>(rs, edata, dinv, m, gb, h, N);

    // ---- Layers 1..2 ----
    for (int l = 1; l < NLAYERS; ++l) {
        const unsigned short* wl = gwt + (size_t)l * HDIM * HDIM;
        const float* bl = gb + (size_t)l * HDIM;
        gemm_lds_k<HDIM, false, false><<<ggrid, 512, 0, stream>>>(h, wl, nullptr, m);
        if (l < NLAYERS - 1)
            gather_k<false><<<(N + 3) / 4, 256, 0, stream>>>(rs, edata, dinv, m, bl, h, N);
        else
            gather_k<true><<<(N + 3) / 4, 256, 0, stream>>>(rs, edata, dinv, m, bl, d_out, N);
    }
}

// Round 5
// 436.314 us; speedup vs baseline: 1.1106x; 1.1106x over previous
//
#include <hip/hip_runtime.h>
#include <hip/hip_bf16.h>

// Problem constants
#define NNODES 100000
#define NEDGES 300000
#define FIN 128
#define HDIM 256
#define NLAYERS 3
#define MPAD 100096  // 782 * 128 — all GEMMs compute exactly MPAD rows, no predicates

typedef float f32x4 __attribute__((ext_vector_type(4)));
typedef short bf16x8 __attribute__((ext_vector_type(8)));

__device__ inline float bf2f(unsigned short u) {
    union { unsigned int i; float f; } v;
    v.i = ((unsigned int)u) << 16;
    return v.f;
}
__device__ inline unsigned short f2bf(float f) {  // RNE
    union { float f; unsigned int i; } v;
    v.f = f;
    return (unsigned short)((v.i + 0x7fffu + ((v.i >> 16) & 1u)) >> 16);
}

// 16-byte async global->LDS (dest = wave-uniform base + lane*16)
__device__ __forceinline__ void gll16(const unsigned short* g, unsigned short* l) {
    __builtin_amdgcn_global_load_lds(
        (const __attribute__((address_space(1))) unsigned int*)g,
        (__attribute__((address_space(3))) unsigned int*)l, 16, 0, 0);
}

// ---------------------------------------------------------------------------
// Counted-vmcnt pipelined MFMA GEMM (R3 structure, unchanged schedule).
// 128x128 tile, 4 waves (wave = 64x64 via 4x4 of 16x16x32 MFMA), BK=32,
// TRIPLE-buffered LDS (48 KiB -> 3 blocks/CU, 12 waves/CU).
// Per K-step: vmcnt(4) [stage(t) drained; stage(t+1) in flight] -> s_barrier
// -> issue stage(t+2) -> ds_read buf[t%3] -> 16 MFMA.
// Race audit: reads at iter t hit buf[t%3]; stage(t+2) issued AFTER
// barrier(t); that buffer's readers (iter t-1) all retired pre-barrier.
// XCD PAIR-SWIZZLE: 1-D grid, bid = 16t + 8x + u (u=0..7), y = 8t+u.
// The two col-tiles (x=0/1) of row-panel y sit 8 apart -> same XCD under
// round-robin dispatch, co-resident -> the second one reads A from L2
// instead of refetching through L3/HBM. Whole-block early-exit for y>=my
// happens before any barrier (uniform).
// Staging: global_load_lds w=16, LINEAR LDS dest; ds_read_b128 conflicts
// avoided by pre-swizzled global SOURCE + same XOR on read (slot ^= (row>>1)&3).
// A: bf16 [.][K] row-major.  Bt: bf16 [256][K] (pre-transposed).  C: bf16.
// ---------------------------------------------------------------------------
template <int K, bool BIAS, bool RELU>
__global__ __launch_bounds__(256) void gemm_lds_k(
    const unsigned short* __restrict__ A, const unsigned short* __restrict__ Bt,
    const float* __restrict__ bias, unsigned short* __restrict__ C, int my) {
    constexpr int BK = 32;        // 64 B per LDS row
    constexpr int NT = K / BK;    // 4 (K=128) or 8 (K=256)
    __shared__ unsigned short sA[3][128 * BK];
    __shared__ unsigned short sB[3][128 * BK];

    const int bid   = blockIdx.x;
    const int ytile = (bid >> 4) * 8 + (bid & 7);
    if (ytile >= my) return;               // uniform whole-block exit, pre-barrier
    const int xcol  = (bid >> 3) & 1;
    const int rowblk = ytile * 128;
    const int colblk = xcol * 128;

    const int tid  = threadIdx.x;
    const int lane = tid & 63;
    const int wid  = tid >> 6;
    const int r15  = lane & 15;
    const int kq   = lane >> 4;        // 0..3
    const int wr   = wid >> 1;         // wave row-tile (0/1)
    const int wc   = wid & 1;          // wave col-tile (0/1)

    // Staging geometry: wave w, chunk q covers LDS rows [q*64 + w*16, +16),
    // each row = 64 B; lane L writes row (L>>2), phys slot (L&3).
    // Phys slot p at row r holds logical k-slot p ^ ((r>>1)&3)  (involution).
    const unsigned short* gA[2];
    const unsigned short* gB[2];
    int ldsbase[2];
#pragma unroll
    for (int q = 0; q < 2; ++q) {
        int rr   = q * 64 + wid * 16 + (lane >> 2);
        int slot = (lane & 3) ^ ((rr >> 1) & 3);
        gA[q] = A  + (size_t)(rowblk + rr) * K + slot * 8;
        gB[q] = Bt + (size_t)(colblk + rr) * K + slot * 8;
        ldsbase[q] = (q * 64 + wid * 16) * BK;   // wave-uniform
    }

    // Read-side swizzled fragment offsets (elements)
    const int sread = ((kq ^ ((r15 >> 1) & 3)) * 8);
    int aoff[4], boff[4];
#pragma unroll
    for (int i = 0; i < 4; ++i) {
        aoff[i] = (wr * 64 + i * 16 + r15) * BK + sread;
        boff[i] = (wc * 64 + i * 16 + r15) * BK + sread;
    }

    f32x4 acc[4][4] = {};

    // prologue: stage K-tiles 0 and 1 into bufs 0 and 1 (8 loads in flight)
#pragma unroll
    for (int q = 0; q < 2; ++q) {
        gll16(gA[q], &sA[0][ldsbase[q]]);
        gll16(gB[q], &sB[0][ldsbase[q]]);
    }
#pragma unroll
    for (int q = 0; q < 2; ++q) {
        gll16(gA[q] + BK, &sA[1][ldsbase[q]]);
        gll16(gB[q] + BK, &sB[1][ldsbase[q]]);
    }

#pragma unroll
    for (int t = 0; t < NT; ++t) {
        // counted drain: only stage(t) must have landed; stage(t+1) stays in flight
        if (t + 1 < NT) {
            asm volatile("s_waitcnt vmcnt(4)" ::: "memory");
        } else {
            asm volatile("s_waitcnt vmcnt(0)" ::: "memory");
        }
        __builtin_amdgcn_s_barrier();
        // issue stage(t+2) AFTER the barrier (its buffer's last readers were
        // iter t-1, all retired before any wave passed this barrier)
        if (t + 2 < NT) {
#pragma unroll
            for (int q = 0; q < 2; ++q) {
                gll16(gA[q] + (t + 2) * BK, &sA[(t + 2) % 3][ldsbase[q]]);
                gll16(gB[q] + (t + 2) * BK, &sB[(t + 2) % 3][ldsbase[q]]);
            }
        }
        bf16x8 a[4], b[4];
#pragma unroll
        for (int i = 0; i < 4; ++i) a[i] = *(const bf16x8*)&sA[t % 3][aoff[i]];
#pragma unroll
        for (int j = 0; j < 4; ++j) b[j] = *(const bf16x8*)&sB[t % 3][boff[j]];
#pragma unroll
        for (int i = 0; i < 4; ++i)
#pragma unroll
            for (int j = 0; j < 4; ++j)
                acc[i][j] = __builtin_amdgcn_mfma_f32_16x16x32_bf16(a[i], b[j], acc[i][j], 0, 0, 0);
    }

    // Epilogue: C/D layout col = lane&15, row = (lane>>4)*4 + reg
#pragma unroll
    for (int i = 0; i < 4; ++i) {
#pragma unroll
        for (int reg = 0; reg < 4; ++reg) {
            int row = rowblk + wr * 64 + i * 16 + kq * 4 + reg;
#pragma unroll
            for (int j = 0; j < 4; ++j) {
                int col = colblk + wc * 64 + j * 16 + r15;
                float v = acc[i][j][reg];
                if (BIAS) v += bias[col];
                if (RELU) v = fmaxf(v, 0.0f);
                C[(size_t)row * HDIM + col] = f2bf(v);
            }
        }
    }
}

// ---------------------------------------------------------------------------
// Merged prep kernel: partitioned by blockIdx over 5 independent jobs:
//   [0,128):    wprep w1 -> w1t  (transpose+convert, K=FIN)
//   [128,896):  wprep gw -> gwt  (3 mats, K=HDIM)
//   [896,960):  conv w2 -> w2c   (fp32->bf16, x4)
//   [960,1351): zero cnt (NNODES)
//   [1351]:     foldbias fb[c] = sum_j b2[j]*G0[j][c]
// Replaces 5 serial launches with 1; jobs run concurrently.
// ---------------------------------------------------------------------------
__global__ __launch_bounds__(256) void prep_k(
    const float* __restrict__ w1, unsigned short* __restrict__ w1t,
    const float* __restrict__ gw, unsigned short* __restrict__ gwt,
    const float* __restrict__ w2, unsigned short* __restrict__ w2c,
    const float* __restrict__ b2, float* __restrict__ foldb,
    unsigned* __restrict__ cnt) {
    int b = blockIdx.x;
    int tid = threadIdx.x;
    if (b < 128) {                       // wprep w1: [FIN][256] -> [256][FIN]
        int i = b * 256 + tid;           // < 32768
        int k = i >> 8, p = i & 255;
        w1t[(size_t)p * FIN + k] = f2bf(w1[i]);
    } else if (b < 896) {                // wprep gw: [3][256][256] -> [3][256][256]^T
        int i = (b - 128) * 256 + tid;   // < 196608
        int mat = i >> 16;               // /65536
        int r = i & 65535;
        int k = r >> 8, p = r & 255;
        gwt[(size_t)mat * 65536 + (size_t)p * HDIM + k] = f2bf(gw[i]);
    } else if (b < 960) {                // conv w2 (x4): 16384 float4s
        int i = (b - 896) * 256 + tid;
        float4 v = ((const float4*)w2)[i];
        ushort4 u;
        u.x = f2bf(v.x); u.y = f2bf(v.y); u.z = f2bf(v.z); u.w = f2bf(v.w);
        ((ushort4*)w2c)[i] = u;
    } else if (b < 1351) {               // zero cnt
        int i = (b - 960) * 256 + tid;
        if (i < NNODES) cnt[i] = 0u;
    } else {                             // foldbias (one block)
        int c = tid;
        float s = 0.0f;
#pragma unroll 8
        for (int j = 0; j < HDIM; ++j) s += b2[j] * gw[(size_t)j * HDIM + c];
        foldb[c] = s;
    }
}

// Straight fp32 -> bf16 convert (no transpose), vectorized x4
__global__ void conv_k(const float* __restrict__ W, unsigned short* __restrict__ o, int n4) {
    int i = blockIdx.x * blockDim.x + threadIdx.x;
    if (i >= n4) return;
    float4 v = ((const float4*)W)[i];
    ushort4 u;
    u.x = f2bf(v.x); u.y = f2bf(v.y); u.z = f2bf(v.z); u.w = f2bf(v.w);
    ((ushort4*)o)[i] = u;
}

// ---------------------------------------------------------------------------
// CSR build utilities
// ---------------------------------------------------------------------------
__global__ void count_k(const int* __restrict__ dst, unsigned* __restrict__ cnt, int E) {
    int e = blockIdx.x * blockDim.x + threadIdx.x;
    if (e < E) atomicAdd(&cnt[dst[e]], 1u);
}

// scan1 also computes dinv and zeroes cnt (cursor reuse) — saves 2 launches
__global__ __launch_bounds__(256) void scan1_k(unsigned* __restrict__ cnt,
                                               int* __restrict__ rs,
                                               unsigned* __restrict__ blocksum,
                                               float* __restrict__ dinv, int N) {
    __shared__ unsigned tmp[256];
    int tid = threadIdx.x;
    int gid = blockIdx.x * 256 + tid;
    unsigned v = (gid < N) ? cnt[gid] : 0u;
    if (gid < N) {
        dinv[gid] = 1.0f / sqrtf((float)(v + 1u));  // +1 = self loop
        cnt[gid] = 0u;                               // reset for cursor use
    }
    tmp[tid] = v;
    __syncthreads();
#pragma unroll
    for (int off = 1; off < 256; off <<= 1) {
        unsigned t = (tid >= off) ? tmp[tid - off] : 0u;
        __syncthreads();
        tmp[tid] += t;
        __syncthreads();
    }
    if (gid < N) rs[gid] = (int)(tmp[tid] - v);
    if (tid == 255) blocksum[blockIdx.x] = tmp[tid];
}

__global__ __launch_bounds__(512) void scan2_k(unsigned* __restrict__ blocksum, int nb) {
    __shared__ unsigned tmp[512];
    int tid = threadIdx.x;
    unsigned v = (tid < nb) ? blocksum[tid] : 0u;
    tmp[tid] = v;
    __syncthreads();
#pragma unroll
    for (int off = 1; off < 512; off <<= 1) {
        unsigned t = (tid >= off) ? tmp[tid - off] : 0u;
        __syncthreads();
        tmp[tid] += t;
        __syncthreads();
    }
    if (tid < nb) blocksum[tid] = tmp[tid] - v;
}

__global__ void scan3_k(int* __restrict__ rs, const unsigned* __restrict__ blocksum, int N, int E) {
    int gid = blockIdx.x * blockDim.x + threadIdx.x;
    if (gid < N) rs[gid] += (int)blocksum[gid >> 8];
    if (gid == 0) rs[N] = E;
}

// fill_k packs (src, weight) into one int2 per edge — single 8B load in gather
__global__ void fill_k(const int* __restrict__ src, const int* __restrict__ dst,
                       const int* __restrict__ rs, unsigned* __restrict__ cursor,
                       const float* __restrict__ dinv,
                       int2* __restrict__ edata, int E) {
    int e = blockIdx.x * blockDim.x + threadIdx.x;
    if (e >= E) return;
    int s = src[e], d = dst[e];
    int pos = rs[d] + (int)atomicAdd(&cursor[d], 1u);
    float w = dinv[s] * dinv[d];
    edata[pos] = make_int2(s, __float_as_int(w));
}

// ---------------------------------------------------------------------------
// CSR gather-aggregate (bf16 m), fused self-loop + bias + ReLU.
// One wave per node; ushort4 (4 cols) per lane.
// Cooperative edge-metadata load + register shuffle broadcast + 4-wide
// unrolled independent row gathers. Masked slots carry (s=0, w=0.0).
// ---------------------------------------------------------------------------
template <bool OUTF32>
__global__ __launch_bounds__(256) void gather_k(const int* __restrict__ rs,
                                                const int2* __restrict__ edata,
                                                const float* __restrict__ dinv,
                                                const unsigned short* __restrict__ m,
                                                const float* __restrict__ bias,
                                                void* __restrict__ out, int N) {
    int node = blockIdx.x * 4 + (threadIdx.x >> 6);
    int lane = threadIdx.x & 63;
    if (node >= N) return;
    int beg = rs[node], end = rs[node + 1];
    float d = dinv[node];
    float w0 = d * d;
    ushort4 u = ((const ushort4*)(m + (size_t)node * HDIM))[lane];
    float ax = bf2f(u.x) * w0, ay = bf2f(u.y) * w0, az = bf2f(u.z) * w0, aw = bf2f(u.w) * w0;

    for (int base = beg; base < end; base += 64) {
        int2 ed = (base + lane < end) ? edata[base + lane] : make_int2(0, 0);
        int take = end - base;
        if (take > 64) take = 64;
        for (int e = 0; e < take; e += 4) {
            int s0 = __shfl(ed.x, e + 0);
            int s1 = __shfl(ed.x, e + 1);
            int s2 = __shfl(ed.x, e + 2);
            int s3 = __shfl(ed.x, e + 3);
            float wq0 = __int_as_float(__shfl(ed.y, e + 0));
            float wq1 = __int_as_float(__shfl(ed.y, e + 1));
            float wq2 = __int_as_float(__shfl(ed.y, e + 2));
            float wq3 = __int_as_float(__shfl(ed.y, e + 3));
            ushort4 v0 = ((const ushort4*)(m + (size_t)s0 * HDIM))[lane];
            ushort4 v1 = ((const ushort4*)(m + (size_t)s1 * HDIM))[lane];
            ushort4 v2 = ((const ushort4*)(m + (size_t)s2 * HDIM))[lane];
            ushort4 v3 = ((const ushort4*)(m + (size_t)s3 * HDIM))[lane];
            ax += bf2f(v0.x) * wq0; ay += bf2f(v0.y) * wq0;
            az += bf2f(v0.z) * wq0; aw += bf2f(v0.w) * wq0;
            ax += bf2f(v1.x) * wq1; ay += bf2f(v1.y) * wq1;
            az += bf2f(v1.z) * wq1; aw += bf2f(v1.w) * wq1;
            ax += bf2f(v2.x) * wq2; ay += bf2f(v2.y) * wq2;
            az += bf2f(v2.z) * wq2; aw += bf2f(v2.w) * wq2;
            ax += bf2f(v3.x) * wq3; ay += bf2f(v3.y) * wq3;
            az += bf2f(v3.z) * wq3; aw += bf2f(v3.w) * wq3;
        }
    }

    float4 b = ((const float4*)bias)[lane];
    ax = fmaxf(ax + b.x, 0.0f);
    ay = fmaxf(ay + b.y, 0.0f);
    az = fmaxf(az + b.z, 0.0f);
    aw = fmaxf(aw + b.w, 0.0f);
    if (OUTF32) {
        float4 o = {ax, ay, az, aw};
        ((float4*)out)[(size_t)node * 64 + lane] = o;
    } else {
        ushort4 o;
        o.x = f2bf(ax); o.y = f2bf(ay); o.z = f2bf(az); o.w = f2bf(aw);
        ((ushort4*)out)[(size_t)node * 64 + lane] = o;
    }
}

extern "C" void kernel_launch(void* const* d_in, const int* in_sizes, int n_in,
                              void* d_out, int out_size, void* d_ws, size_t ws_size,
                              hipStream_t stream) {
    const float* x  = (const float*)d_in[0];
    const int* ei   = (const int*)d_in[1];
    const float* w1 = (const float*)d_in[2];
    const float* b1 = (const float*)d_in[3];
    const float* w2 = (const float*)d_in[4];
    const float* b2 = (const float*)d_in[5];
    const float* gw = (const float*)d_in[6];
    const float* gb = (const float*)d_in[7];

    const int N = NNODES, E = NEDGES;
    const int* src = ei;
    const int* dst = ei + E;

    // Workspace layout (~158 MB)
    char* p = (char*)d_ws;
    unsigned short* h1   = (unsigned short*)p; p += (size_t)MPAD * HDIM * 2;  // 51.2 MB
    unsigned short* h    = (unsigned short*)p; p += (size_t)MPAD * HDIM * 2;
    unsigned short* m    = (unsigned short*)p; p += (size_t)MPAD * HDIM * 2;
    unsigned short* w1t  = (unsigned short*)p; p += (size_t)FIN * HDIM * 2;
    unsigned short* gwt  = (unsigned short*)p; p += (size_t)NLAYERS * HDIM * HDIM * 2;
    unsigned short* w2c  = (unsigned short*)p; p += (size_t)HDIM * HDIM * 2;   // w2 bf16 row-major
    unsigned short* fBt  = (unsigned short*)p; p += (size_t)HDIM * HDIM * 2;   // folded W2*G0, Bt layout
    float* foldb = (float*)p;          p += (size_t)HDIM * 4;                  // folded bias b2*G0
    unsigned* cnt = (unsigned*)p;      p += (size_t)N * 4;
    float* dinv = (float*)p;           p += (size_t)N * 4;
    int* rs = (int*)p;                 p += (size_t)(N + 1) * 4 + 12;
    unsigned* blocksum = (unsigned*)p; p += 512 * 4;
    int2* edata = (int2*)p;            p += (size_t)E * 8;   // packed (src, weight)

    // xb: x converted to bf16 [MPAD][FIN] — reuses the idle m buffer (25.6 MB < 51.2 MB)
    unsigned short* xb = m;

    const int nb = (N + 255) / 256;             // 391
    const int MY = MPAD / 128;                  // 782 row-tiles
    const int ggrid = 16 * ((MY + 7) / 8);      // 1568 (pair-swizzled 1-D grid)

    // ---- Merged prep (wprep w1, wprep gw, conv w2, zero cnt, foldbias) + x->bf16 ----
    prep_k<<<1352, 256, 0, stream>>>(w1, w1t, gw, gwt, w2, w2c, b2, foldb, cnt);
    conv_k<<<(N * FIN / 4 + 255) / 256, 256, 0, stream>>>(x, xb, N * FIN / 4);

    // ---- Fold: fBt[c][k'] = sum_j G0[j][c]*W2[k'][j]  (my=2 -> grid 16, 12 blocks idle)
    gemm_lds_k<HDIM, false, false><<<16, 256, 0, stream>>>(gwt, w2c, nullptr, fBt, 2);

    // ---- CSR build ----
    count_k<<<(E + 255) / 256, 256, 0, stream>>>(dst, cnt, E);
    scan1_k<<<nb, 256, 0, stream>>>(cnt, rs, blocksum, dinv, N);
    scan2_k<<<1, 512, 0, stream>>>(blocksum, nb);
    scan3_k<<<nb + 1, 256, 0, stream>>>(rs, blocksum, N, E);
    fill_k<<<(E + 255) / 256, 256, 0, stream>>>(src, dst, rs, cnt, dinv, edata, E);

    // ---- Encoder GEMM1: h1 = relu(xb @ W1 + b1) ----
    gemm_lds_k<FIN, true, true><<<ggrid, 256, 0, stream>>>(xb, w1t, b1, h1, MY);

    // ---- Layer 0 (folded): m = h1 @ (W2*G0) + b2*G0  (overwrites xb — already consumed)
    gemm_lds_k<HDIM, true, false><<<ggrid, 256, 0, stream>>>(h1, fBt, foldb, m, MY);
    gather_k<false><<<(N + 3) / 4, 256, 0, stream>>>(rs, edata, dinv, m, gb, h, N);

    // ---- Layers 1..2 ----
    for (int l = 1; l < NLAYERS; ++l) {
        const unsigned short* wl = gwt + (size_t)l * HDIM * HDIM;
        const float* bl = gb + (size_t)l * HDIM;
        gemm_lds_k<HDIM, false, false><<<ggrid, 256, 0, stream>>>(h, wl, nullptr, m, MY);
        if (l < NLAYERS - 1)
            gather_k<false><<<(N + 3) / 4, 256, 0, stream>>>(rs, edata, dinv, m, bl, h, N);
        else
            gather_k<true><<<(N + 3) / 4, 256, 0, stream>>>(rs, edata, dinv, m, bl, d_out, N);
    }
}

// Round 6
// 421.564 us; speedup vs baseline: 1.1494x; 1.0350x over previous
//
#include <hip/hip_runtime.h>
#include <hip/hip_bf16.h>

// Problem constants
#define NNODES 100000
#define NEDGES 300000
#define FIN 128
#define HDIM 256
#define NLAYERS 3
#define MPAD 100096  // 782 * 128 — all GEMMs compute exactly MPAD rows, no predicates

typedef float f32x4 __attribute__((ext_vector_type(4)));
typedef short bf16x8 __attribute__((ext_vector_type(8)));

__device__ inline float bf2f(unsigned short u) {
    union { unsigned int i; float f; } v;
    v.i = ((unsigned int)u) << 16;
    return v.f;
}
__device__ inline unsigned short f2bf(float f) {  // RNE
    union { float f; unsigned int i; } v;
    v.f = f;
    return (unsigned short)((v.i + 0x7fffu + ((v.i >> 16) & 1u)) >> 16);
}

// 16-byte async global->LDS (dest = wave-uniform base + lane*16)
__device__ __forceinline__ void gll16(const unsigned short* g, unsigned short* l) {
    __builtin_amdgcn_global_load_lds(
        (const __attribute__((address_space(1))) unsigned int*)g,
        (__attribute__((address_space(3))) unsigned int*)l, 16, 0, 0);
}

// ---------------------------------------------------------------------------
// Counted-vmcnt pipelined MFMA GEMM (R3 structure + R5 XCD pair-swizzle).
// 128x128 tile, 4 waves, BK=32, TRIPLE-buffered LDS (48 KiB, 3 blocks/CU).
// Per K-step: vmcnt(4) -> s_barrier -> issue stage(t+2) -> ds_read buf[t%3]
// -> 16 MFMA.  (Race audit in R3 notes; unchanged.)
// XCD PAIR-SWIZZLE: 1-D grid, bid = 16t + 8x + u (u=0..7), y = 8t+u; the two
// col-tiles of row-panel y sit 8 apart -> same XCD, co-resident -> A L2-hits.
// ---------------------------------------------------------------------------
template <int K, bool BIAS, bool RELU>
__global__ __launch_bounds__(256) void gemm_lds_k(
    const unsigned short* __restrict__ A, const unsigned short* __restrict__ Bt,
    const float* __restrict__ bias, unsigned short* __restrict__ C, int my) {
    constexpr int BK = 32;        // 64 B per LDS row
    constexpr int NT = K / BK;    // 4 (K=128) or 8 (K=256)
    __shared__ unsigned short sA[3][128 * BK];
    __shared__ unsigned short sB[3][128 * BK];

    const int bid   = blockIdx.x;
    const int ytile = (bid >> 4) * 8 + (bid & 7);
    if (ytile >= my) return;               // uniform whole-block exit, pre-barrier
    const int xcol  = (bid >> 3) & 1;
    const int rowblk = ytile * 128;
    const int colblk = xcol * 128;

    const int tid  = threadIdx.x;
    const int lane = tid & 63;
    const int wid  = tid >> 6;
    const int r15  = lane & 15;
    const int kq   = lane >> 4;        // 0..3
    const int wr   = wid >> 1;         // wave row-tile (0/1)
    const int wc   = wid & 1;          // wave col-tile (0/1)

    // Staging geometry: wave w, chunk q covers LDS rows [q*64 + w*16, +16),
    // each row = 64 B; lane L writes row (L>>2), phys slot (L&3).
    // Phys slot p at row r holds logical k-slot p ^ ((r>>1)&3)  (involution).
    const unsigned short* gA[2];
    const unsigned short* gB[2];
    int ldsbase[2];
#pragma unroll
    for (int q = 0; q < 2; ++q) {
        int rr   = q * 64 + wid * 16 + (lane >> 2);
        int slot = (lane & 3) ^ ((rr >> 1) & 3);
        gA[q] = A  + (size_t)(rowblk + rr) * K + slot * 8;
        gB[q] = Bt + (size_t)(colblk + rr) * K + slot * 8;
        ldsbase[q] = (q * 64 + wid * 16) * BK;   // wave-uniform
    }

    // Read-side swizzled fragment offsets (elements)
    const int sread = ((kq ^ ((r15 >> 1) & 3)) * 8);
    int aoff[4], boff[4];
#pragma unroll
    for (int i = 0; i < 4; ++i) {
        aoff[i] = (wr * 64 + i * 16 + r15) * BK + sread;
        boff[i] = (wc * 64 + i * 16 + r15) * BK + sread;
    }

    f32x4 acc[4][4] = {};

    // prologue: stage K-tiles 0 and 1 into bufs 0 and 1 (8 loads in flight)
#pragma unroll
    for (int q = 0; q < 2; ++q) {
        gll16(gA[q], &sA[0][ldsbase[q]]);
        gll16(gB[q], &sB[0][ldsbase[q]]);
    }
#pragma unroll
    for (int q = 0; q < 2; ++q) {
        gll16(gA[q] + BK, &sA[1][ldsbase[q]]);
        gll16(gB[q] + BK, &sB[1][ldsbase[q]]);
    }

#pragma unroll
    for (int t = 0; t < NT; ++t) {
        // counted drain: only stage(t) must have landed; stage(t+1) stays in flight
        if (t + 1 < NT) {
            asm volatile("s_waitcnt vmcnt(4)" ::: "memory");
        } else {
            asm volatile("s_waitcnt vmcnt(0)" ::: "memory");
        }
        __builtin_amdgcn_s_barrier();
        // issue stage(t+2) AFTER the barrier (its buffer's last readers were
        // iter t-1, all retired before any wave passed this barrier)
        if (t + 2 < NT) {
#pragma unroll
            for (int q = 0; q < 2; ++q) {
                gll16(gA[q] + (t + 2) * BK, &sA[(t + 2) % 3][ldsbase[q]]);
                gll16(gB[q] + (t + 2) * BK, &sB[(t + 2) % 3][ldsbase[q]]);
            }
        }
        bf16x8 a[4], b[4];
#pragma unroll
        for (int i = 0; i < 4; ++i) a[i] = *(const bf16x8*)&sA[t % 3][aoff[i]];
#pragma unroll
        for (int j = 0; j < 4; ++j) b[j] = *(const bf16x8*)&sB[t % 3][boff[j]];
#pragma unroll
        for (int i = 0; i < 4; ++i)
#pragma unroll
            for (int j = 0; j < 4; ++j)
                acc[i][j] = __builtin_amdgcn_mfma_f32_16x16x32_bf16(a[i], b[j], acc[i][j], 0, 0, 0);
    }

    // Epilogue: C/D layout col = lane&15, row = (lane>>4)*4 + reg
#pragma unroll
    for (int i = 0; i < 4; ++i) {
#pragma unroll
        for (int reg = 0; reg < 4; ++reg) {
            int row = rowblk + wr * 64 + i * 16 + kq * 4 + reg;
#pragma unroll
            for (int j = 0; j < 4; ++j) {
                int col = colblk + wc * 64 + j * 16 + r15;
                float v = acc[i][j][reg];
                if (BIAS) v += bias[col];
                if (RELU) v = fmaxf(v, 0.0f);
                C[(size_t)row * HDIM + col] = f2bf(v);
            }
        }
    }
}

// ---------------------------------------------------------------------------
// Merged prep kernel, partitioned by blockIdx over 6 independent jobs:
//   [0,12500):      conv x -> xb   (fp32->bf16, x4)   [N*FIN/4 = 3.2M items]
//   [12500,12628):  wprep w1 -> w1t  (transpose+convert, K=FIN)
//   [12628,13396):  wprep gw -> gwt  (3 mats, K=HDIM)
//   [13396,13460):  conv w2 -> w2c
//   [13460,13851):  zero cnt (NNODES)
//   [13851]:        foldbias fb[c] = sum_j b2[j]*G0[j][c]
// ---------------------------------------------------------------------------
__global__ __launch_bounds__(256) void prep_k(
    const float* __restrict__ x, unsigned short* __restrict__ xb,
    const float* __restrict__ w1, unsigned short* __restrict__ w1t,
    const float* __restrict__ gw, unsigned short* __restrict__ gwt,
    const float* __restrict__ w2, unsigned short* __restrict__ w2c,
    const float* __restrict__ b2, float* __restrict__ foldb,
    unsigned* __restrict__ cnt) {
    int b = blockIdx.x;
    int tid = threadIdx.x;
    if (b < 12500) {                     // conv x (x4)
        int i = b * 256 + tid;           // < 3,200,000
        float4 v = ((const float4*)x)[i];
        ushort4 u;
        u.x = f2bf(v.x); u.y = f2bf(v.y); u.z = f2bf(v.z); u.w = f2bf(v.w);
        ((ushort4*)xb)[i] = u;
    } else if (b < 12628) {              // wprep w1: [FIN][256] -> [256][FIN]
        int i = (b - 12500) * 256 + tid; // < 32768
        int k = i >> 8, p = i & 255;
        w1t[(size_t)p * FIN + k] = f2bf(w1[i]);
    } else if (b < 13396) {              // wprep gw: [3][256][256] -> transposed
        int i = (b - 12628) * 256 + tid; // < 196608
        int mat = i >> 16;
        int r = i & 65535;
        int k = r >> 8, p = r & 255;
        gwt[(size_t)mat * 65536 + (size_t)p * HDIM + k] = f2bf(gw[i]);
    } else if (b < 13460) {              // conv w2 (x4): 16384 float4s
        int i = (b - 13396) * 256 + tid;
        float4 v = ((const float4*)w2)[i];
        ushort4 u;
        u.x = f2bf(v.x); u.y = f2bf(v.y); u.z = f2bf(v.z); u.w = f2bf(v.w);
        ((ushort4*)w2c)[i] = u;
    } else if (b < 13851) {              // zero cnt
        int i = (b - 13460) * 256 + tid;
        if (i < NNODES) cnt[i] = 0u;
    } else {                             // foldbias (one block)
        int c = tid;
        float s = 0.0f;
#pragma unroll 8
        for (int j = 0; j < HDIM; ++j) s += b2[j] * gw[(size_t)j * HDIM + c];
        foldb[c] = s;
    }
}

// ---------------------------------------------------------------------------
// CSR build utilities
// ---------------------------------------------------------------------------
__global__ void count_k(const int* __restrict__ dst, unsigned* __restrict__ cnt, int E) {
    int e = blockIdx.x * blockDim.x + threadIdx.x;
    if (e < E) atomicAdd(&cnt[dst[e]], 1u);
}

// scan1 also computes dinv and zeroes cnt (cursor reuse) — saves 2 launches
__global__ __launch_bounds__(256) void scan1_k(unsigned* __restrict__ cnt,
                                               int* __restrict__ rs,
                                               unsigned* __restrict__ blocksum,
                                               float* __restrict__ dinv, int N) {
    __shared__ unsigned tmp[256];
    int tid = threadIdx.x;
    int gid = blockIdx.x * 256 + tid;
    unsigned v = (gid < N) ? cnt[gid] : 0u;
    if (gid < N) {
        dinv[gid] = 1.0f / sqrtf((float)(v + 1u));  // +1 = self loop
        cnt[gid] = 0u;                               // reset for cursor use
    }
    tmp[tid] = v;
    __syncthreads();
#pragma unroll
    for (int off = 1; off < 256; off <<= 1) {
        unsigned t = (tid >= off) ? tmp[tid - off] : 0u;
        __syncthreads();
        tmp[tid] += t;
        __syncthreads();
    }
    if (gid < N) rs[gid] = (int)(tmp[tid] - v);
    if (tid == 255) blocksum[blockIdx.x] = tmp[tid];
}

__global__ __launch_bounds__(512) void scan2_k(unsigned* __restrict__ blocksum, int nb) {
    __shared__ unsigned tmp[512];
    int tid = threadIdx.x;
    unsigned v = (tid < nb) ? blocksum[tid] : 0u;
    tmp[tid] = v;
    __syncthreads();
#pragma unroll
    for (int off = 1; off < 512; off <<= 1) {
        unsigned t = (tid >= off) ? tmp[tid - off] : 0u;
        __syncthreads();
        tmp[tid] += t;
        __syncthreads();
    }
    if (tid < nb) blocksum[tid] = tmp[tid] - v;
}

__global__ void scan3_k(int* __restrict__ rs, const unsigned* __restrict__ blocksum, int N, int E) {
    int gid = blockIdx.x * blockDim.x + threadIdx.x;
    if (gid < N) rs[gid] += (int)blocksum[gid >> 8];
    if (gid == 0) rs[N] = E;
}

// fill_k packs (src, weight) into one int2 per edge — single 8B load in gather
__global__ void fill_k(const int* __restrict__ src, const int* __restrict__ dst,
                       const int* __restrict__ rs, unsigned* __restrict__ cursor,
                       const float* __restrict__ dinv,
                       int2* __restrict__ edata, int E) {
    int e = blockIdx.x * blockDim.x + threadIdx.x;
    if (e >= E) return;
    int s = src[e], d = dst[e];
    int pos = rs[d] + (int)atomicAdd(&cursor[d], 1u);
    float w = dinv[s] * dinv[d];
    edata[pos] = make_int2(s, __float_as_int(w));
}

// ---------------------------------------------------------------------------
// CSR gather-aggregate (bf16 m), fused self-loop + bias + ReLU.
// TWO nodes per wave: half-wave (32 lanes x ushort8 = 512B) per node row.
// Doubles independent latency chains per wave and halves block count
// (12500 blocks, 8 nodes/block -> 6.1 turnover rounds/CU vs 12.2).
// Cooperative half-wave edge-metadata load + half-wave shuffle broadcast +
// 4-wide unrolled independent row gathers. Masked slots carry (s=0, w=0.0):
// weight-0 read of row 0 contributes exactly 0.
// N must be divisible by 8 (100000 = 12500*8) — no tail predicate.
// ---------------------------------------------------------------------------
template <bool OUTF32>
__global__ __launch_bounds__(256) void gather_k(const int* __restrict__ rs,
                                                const int2* __restrict__ edata,
                                                const float* __restrict__ dinv,
                                                const unsigned short* __restrict__ m,
                                                const float* __restrict__ bias,
                                                void* __restrict__ out, int N) {
    const int wid  = threadIdx.x >> 6;   // 0..3
    const int lane = threadIdx.x & 63;
    const int half = lane >> 5;          // 0/1: which node of the pair
    const int hl   = lane & 31;          // lane within half
    const int node = blockIdx.x * 8 + wid * 2 + half;

    const int beg = rs[node], end = rs[node + 1];
    const float d = dinv[node];
    const float w0 = d * d;

    // self row: 32 lanes x ushort8 = 512B
    bf16x8 u = ((const bf16x8*)(m + (size_t)node * HDIM))[hl];
    float acc[8];
#pragma unroll
    for (int j = 0; j < 8; ++j) acc[j] = bf2f((unsigned short)u[j]) * w0;

    for (int base = beg; base < end; base += 32) {
        int2 ed = (base + hl < end) ? edata[base + hl] : make_int2(0, 0);
        int take = end - base;
        if (take > 32) take = 32;
        for (int e = 0; e < take; e += 4) {
            // broadcast from this half's metadata lanes
            int s0 = __shfl(ed.x, half * 32 + e + 0);
            int s1 = __shfl(ed.x, half * 32 + e + 1);
            int s2 = __shfl(ed.x, half * 32 + e + 2);
            int s3 = __shfl(ed.x, half * 32 + e + 3);
            float wq0 = __int_as_float(__shfl(ed.y, half * 32 + e + 0));
            float wq1 = __int_as_float(__shfl(ed.y, half * 32 + e + 1));
            float wq2 = __int_as_float(__shfl(ed.y, half * 32 + e + 2));
            float wq3 = __int_as_float(__shfl(ed.y, half * 32 + e + 3));
            bf16x8 v0 = ((const bf16x8*)(m + (size_t)s0 * HDIM))[hl];
            bf16x8 v1 = ((const bf16x8*)(m + (size_t)s1 * HDIM))[hl];
            bf16x8 v2 = ((const bf16x8*)(m + (size_t)s2 * HDIM))[hl];
            bf16x8 v3 = ((const bf16x8*)(m + (size_t)s3 * HDIM))[hl];
#pragma unroll
            for (int j = 0; j < 8; ++j) {
                acc[j] += bf2f((unsigned short)v0[j]) * wq0;
                acc[j] += bf2f((unsigned short)v1[j]) * wq1;
                acc[j] += bf2f((unsigned short)v2[j]) * wq2;
                acc[j] += bf2f((unsigned short)v3[j]) * wq3;
            }
        }
    }

    // bias + ReLU on 8 cols (hl*8 .. hl*8+7)
    float4 b0 = ((const float4*)bias)[hl * 2];
    float4 b1 = ((const float4*)bias)[hl * 2 + 1];
    acc[0] = fmaxf(acc[0] + b0.x, 0.0f); acc[1] = fmaxf(acc[1] + b0.y, 0.0f);
    acc[2] = fmaxf(acc[2] + b0.z, 0.0f); acc[3] = fmaxf(acc[3] + b0.w, 0.0f);
    acc[4] = fmaxf(acc[4] + b1.x, 0.0f); acc[5] = fmaxf(acc[5] + b1.y, 0.0f);
    acc[6] = fmaxf(acc[6] + b1.z, 0.0f); acc[7] = fmaxf(acc[7] + b1.w, 0.0f);

    if (OUTF32) {
        float4 o0 = {acc[0], acc[1], acc[2], acc[3]};
        float4 o1 = {acc[4], acc[5], acc[6], acc[7]};
        ((float4*)out)[(size_t)node * 64 + hl * 2] = o0;
        ((float4*)out)[(size_t)node * 64 + hl * 2 + 1] = o1;
    } else {
        bf16x8 o;
#pragma unroll
        for (int j = 0; j < 8; ++j) o[j] = (short)f2bf(acc[j]);
        ((bf16x8*)out)[(size_t)node * 32 + hl] = o;
    }
}

extern "C" void kernel_launch(void* const* d_in, const int* in_sizes, int n_in,
                              void* d_out, int out_size, void* d_ws, size_t ws_size,
                              hipStream_t stream) {
    const float* x  = (const float*)d_in[0];
    const int* ei   = (const int*)d_in[1];
    const float* w1 = (const float*)d_in[2];
    const float* b1 = (const float*)d_in[3];
    const float* w2 = (const float*)d_in[4];
    const float* b2 = (const float*)d_in[5];
    const float* gw = (const float*)d_in[6];
    const float* gb = (const float*)d_in[7];

    const int N = NNODES, E = NEDGES;
    const int* src = ei;
    const int* dst = ei + E;

    // Workspace layout (~158 MB)
    char* p = (char*)d_ws;
    unsigned short* h1   = (unsigned short*)p; p += (size_t)MPAD * HDIM * 2;  // 51.2 MB
    unsigned short* h    = (unsigned short*)p; p += (size_t)MPAD * HDIM * 2;
    unsigned short* m    = (unsigned short*)p; p += (size_t)MPAD * HDIM * 2;
    unsigned short* w1t  = (unsigned short*)p; p += (size_t)FIN * HDIM * 2;
    unsigned short* gwt  = (unsigned short*)p; p += (size_t)NLAYERS * HDIM * HDIM * 2;
    unsigned short* w2c  = (unsigned short*)p; p += (size_t)HDIM * HDIM * 2;   // w2 bf16 row-major
    unsigned short* fBt  = (unsigned short*)p; p += (size_t)HDIM * HDIM * 2;   // folded W2*G0, Bt layout
    float* foldb = (float*)p;          p += (size_t)HDIM * 4;                  // folded bias b2*G0
    unsigned* cnt = (unsigned*)p;      p += (size_t)N * 4;
    float* dinv = (float*)p;           p += (size_t)N * 4;
    int* rs = (int*)p;                 p += (size_t)(N + 1) * 4 + 12;
    unsigned* blocksum = (unsigned*)p; p += 512 * 4;
    int2* edata = (int2*)p;            p += (size_t)E * 8;   // packed (src, weight)

    // xb: x converted to bf16 [MPAD][FIN] — reuses the idle m buffer (25.6 MB < 51.2 MB)
    unsigned short* xb = m;

    const int nb = (N + 255) / 256;             // 391
    const int MY = MPAD / 128;                  // 782 row-tiles
    const int ggrid = 16 * ((MY + 7) / 8);      // 1568 (pair-swizzled 1-D grid)

    // ---- Merged prep (conv x, wprep w1, wprep gw, conv w2, zero cnt, foldbias) ----
    prep_k<<<13852, 256, 0, stream>>>(x, xb, w1, w1t, gw, gwt, w2, w2c, b2, foldb, cnt);

    // ---- Fold: fBt[c][k'] = sum_j G0[j][c]*W2[k'][j]  (my=2 -> grid 16, 14 blocks idle)
    gemm_lds_k<HDIM, false, false><<<16, 256, 0, stream>>>(gwt, w2c, nullptr, fBt, 2);

    // ---- CSR build ----
    count_k<<<(E + 255) / 256, 256, 0, stream>>>(dst, cnt, E);
    scan1_k<<<nb, 256, 0, stream>>>(cnt, rs, blocksum, dinv, N);
    scan2_k<<<1, 512, 0, stream>>>(blocksum, nb);
    scan3_k<<<nb + 1, 256, 0, stream>>>(rs, blocksum, N, E);
    fill_k<<<(E + 255) / 256, 256, 0, stream>>>(src, dst, rs, cnt, dinv, edata, E);

    // ---- Encoder GEMM1: h1 = relu(xb @ W1 + b1) ----
    gemm_lds_k<FIN, true, true><<<ggrid, 256, 0, stream>>>(xb, w1t, b1, h1, MY);

    // ---- Layer 0 (folded): m = h1 @ (W2*G0) + b2*G0  (overwrites xb — already consumed)
    gemm_lds_k<HDIM, true, false><<<ggrid, 256, 0, stream>>>(h1, fBt, foldb, m, MY);
    gather_k<false><<<N / 8, 256, 0, stream>>>(rs, edata, dinv, m, gb, h, N);

    // ---- Layers 1..2 ----
    for (int l = 1; l < NLAYERS; ++l) {
        const unsigned short* wl = gwt + (size_t)l * HDIM * HDIM;
        const float* bl = gb + (size_t)l * HDIM;
        gemm_lds_k<HDIM, false, false><<<ggrid, 256, 0, stream>>>(h, wl, nullptr, m, MY);
        if (l < NLAYERS - 1)
            gather_k<false><<<N / 8, 256, 0, stream>>>(rs, edata, dinv, m, bl, h, N);
        else
            gather_k<true><<<N / 8, 256, 0, stream>>>(rs, edata, dinv, m, bl, d_out, N);
    }
}